// Round 12
// baseline (621.506 us; speedup 1.0000x reference)
//
#include <hip/hip_runtime.h>

#define BB 16
#define CIN 32
#define NN 4096
#define TT 12
#define HH 64
#define MM 128
#define DD 64
#define TC (TT*HH)            // 768
#define V1OFF 50331648        // B*H*N*T floats
#define V2OFF 50855936
#define KVELEM (MM*TC)        // 98304 per batch
#define NORMR 0.35355339059327373f   // 64^-0.25
#define RATIO 0.08838834764831845f   // 128^-0.5
#define FEPS 1e-4f

typedef __attribute__((ext_vector_type(8))) short bf16x8;
typedef __attribute__((ext_vector_type(4))) float f32x4;

union BF8 { unsigned short s[8]; bf16x8 v; };

__device__ inline float wave_max(float v) {
#pragma unroll
  for (int off = 32; off > 0; off >>= 1) v = fmaxf(v, __shfl_xor(v, off));
  return v;
}

__device__ inline unsigned short f2bf(float f) {
  unsigned int u = __float_as_uint(f);
  unsigned int r = (u + 0x7FFFu + ((u >> 16) & 1u)) >> 16;
  return (unsigned short)r;
}

// split float into hi/lo bf16 (hi + lo reconstructs to ~2^-17 rel)
__device__ inline void hilo(float v, unsigned short& h, unsigned short& l) {
  h = f2bf(v);
  float fh = __uint_as_float((unsigned int)h << 16);
  l = f2bf(v - fh);
}

// ---- tiny setup kernels -------------------------------------------------

// stack [Wi;Wo] into 128x32 and split hi/lo
__global__ __launch_bounds__(256) void k_wsplit(const float* __restrict__ Wi,
    const float* __restrict__ Wo, unsigned short* __restrict__ whi,
    unsigned short* __restrict__ wlo) {
  int idx = blockIdx.x * 256 + threadIdx.x;   // 4096
  int o = idx >> 5, c = idx & 31;
  float w = (o < 64) ? Wi[o * 32 + c] : Wo[(o - 64) * 32 + c];
  unsigned short h, l; hilo(w, h, l);
  whi[idx] = h; wlo[idx] = l;
}

// K1: per-row features. v1p final (+hi/lo planes); t2 = dash2-diag2 into v2p slot.
__global__ __launch_bounds__(128) void k_feat(const float* __restrict__ nv1,
    const float* __restrict__ nv2, const float* __restrict__ proj,
    float* __restrict__ v1p, float* __restrict__ t2, float* __restrict__ rowmax2,
    unsigned short* __restrict__ v1phi, unsigned short* __restrict__ v1plo) {
  int n = blockIdx.x, m = threadIdx.x;
  __shared__ float a1[DD], a2[DD], r1[2], r2[2];
  if (m < DD) a1[m] = nv1[n * DD + m];
  else        a2[m - DD] = nv2[n * DD + (m - DD)];
  __syncthreads();
  float s1 = 0.f, s2 = 0.f, d1 = 0.f, d2 = 0.f;
  const float* pr = proj + m * DD;
#pragma unroll 8
  for (int d = 0; d < DD; d++) {
    float x1 = a1[d], x2 = a2[d], p = pr[d];
    s1 += x1 * x1; s2 += x2 * x2;
    d1 += x1 * p;  d2 += x2 * p;
  }
  d1 *= NORMR; d2 *= NORMR;
  float diag1 = 0.0625f * s1, diag2 = 0.0625f * s2;
  float mx1 = wave_max(d1), mx2 = wave_max(d2);
  int wv = m >> 6;
  if ((m & 63) == 0) { r1[wv] = mx1; r2[wv] = mx2; }
  __syncthreads();
  mx1 = fmaxf(r1[0], r1[1]); mx2 = fmaxf(r2[0], r2[1]);
  float val = RATIO * (__expf(d1 - diag1 - mx1) + FEPS);
  v1p[n * MM + m] = val;
  unsigned short h, l; hilo(val, h, l);
  v1phi[n * MM + m] = h;
  v1plo[n * MM + m] = l;
  t2[n * MM + m] = d2 - diag2;
  if (m == 0) rowmax2[n] = mx2;
}

// K2: global max of dash2
__global__ __launch_bounds__(256) void k_stab(const float* __restrict__ rowmax2,
                                              float* __restrict__ stab2) {
  int tid = threadIdx.x;
  float mx = -3.4e38f;
  for (int i = tid; i < NN; i += 256) mx = fmaxf(mx, rowmax2[i]);
  mx = wave_max(mx);
  __shared__ float r[4];
  if ((tid & 63) == 0) r[tid >> 6] = mx;
  __syncthreads();
  if (tid == 0) stab2[0] = fmaxf(fmaxf(r[0], r[1]), fmaxf(r[2], r[3]));
}

// K3: finish v2p in place, colsum, and write MFMA-FRAGMENT-PACKED hi/lo
// planes: pack[((n>>5)*4 + ((n>>3)&3))*1024 + m*8 + (n&7)]. Makes k_kv's
// A-loads 256B-contiguous per quarter-wave. Block-disjoint 8KB chunks.
__global__ __launch_bounds__(128) void k_v2p(float* __restrict__ t2v2p,
    const float* __restrict__ stab2, float* __restrict__ colsum,
    unsigned short* __restrict__ v2pkhi, unsigned short* __restrict__ v2pklo) {
  int m = threadIdx.x;
  float stab = stab2[0];
  float cs = 0.f;
  int n0 = blockIdx.x * 64;
  for (int i = 0; i < 64; i++) {
    int n = n0 + i;
    float v = RATIO * (__expf(t2v2p[n * MM + m] - stab) + FEPS);
    t2v2p[n * MM + m] = v;
    cs += v;
    unsigned short h, l; hilo(v, h, l);
    int off = ((n >> 5) * 4 + ((n >> 3) & 3)) * (MM * 8) + m * 8 + (n & 7);
    v2pkhi[off] = h;
    v2pklo[off] = l;
  }
  atomicAdd(&colsum[m], cs);
}

// K4: inv_den[n] = 1 / (v1p[n,:] . colsum)
__global__ __launch_bounds__(256) void k_den(const float* __restrict__ v1p,
    const float* __restrict__ colsum, float* __restrict__ invden) {
  __shared__ float cs[MM];
  int tid = threadIdx.x;
  if (tid < MM) cs[tid] = colsum[tid];
  __syncthreads();
  int n = blockIdx.x * 256 + tid;
  const float* vp = v1p + (size_t)n * MM;
  float s = 0.f;
#pragma unroll 8
  for (int m = 0; m < MM; m++) s += vp[m] * cs[m];
  invden[n] = 1.0f / s;
}

// ---- K5: conv+gate via MFMA. A = stacked W[128x32] hi/lo (regs), B = input.
// x stored hi/lo bf16 planes, layout [b][n/8][j=t*64+h][n%8].
// t-split 3-way; GRID REORDER (t fastest): the 3 blocks sharing each 48B
// input row now dispatch back-to-back, so their shared 64B lines hit in
// L2/L3 instead of re-fetching (was FETCH 147.8MB vs 100.7MB ideal).
__global__ __launch_bounds__(256) void k_point(const float* __restrict__ inp,
    const unsigned short* __restrict__ whi, const unsigned short* __restrict__ wlo,
    const float* __restrict__ bi, const float* __restrict__ bo,
    unsigned short* __restrict__ xhi, unsigned short* __restrict__ xlo) {
  int tid = threadIdx.x;
  int wv = tid >> 6, lane = tid & 63;
  int quad = lane >> 4, l16 = lane & 15;
  int t0 = blockIdx.x * 4;              // {0,4,8}: fastest dim for row sharing
  int b = blockIdx.z;
  int n = blockIdx.y * 64 + wv * 16 + l16;

  bf16x8 wh[8], wl[8];
#pragma unroll
  for (int tile = 0; tile < 8; tile++) {
    int m = tile * 16 + l16;
    wh[tile] = *(const bf16x8*)(whi + m * 32 + quad * 8);
    wl[tile] = *(const bf16x8*)(wlo + m * 32 + quad * 8);
  }
  f32x4 binit[8];
#pragma unroll
  for (int tile = 0; tile < 8; tile++) {
    const float* bp = (tile < 4) ? bi : bo;
#pragma unroll
    for (int r = 0; r < 4; r++)
      binit[tile][r] = bp[(tile & 3) * 16 + quad * 4 + r];
  }
  const float* ipb = inp + ((size_t)b * CIN + quad * 8) * (NN * TT) + (size_t)n * TT + t0;

  // preload this block's 4 t for the 8 channels of this quad; convert once.
  BF8 xh[4], xl[4];
#pragma unroll
  for (int j = 0; j < 8; j++) {
    float4 r0 = *(const float4*)(ipb + (size_t)j * (NN * TT));
    float row[4] = {r0.x, r0.y, r0.z, r0.w};
#pragma unroll
    for (int tt = 0; tt < 4; tt++) {
      unsigned short h, l; hilo(row[tt], h, l);
      xh[tt].s[j] = h; xl[tt].s[j] = l;
    }
  }

  size_t xbase = ((size_t)(b * (NN / 8) + (n >> 3)) * TC) * 8 + (n & 7);
#pragma unroll
  for (int tt = 0; tt < 4; tt++) {
    int t = t0 + tt;
    f32x4 acc[8];
#pragma unroll
    for (int tile = 0; tile < 8; tile++) acc[tile] = binit[tile];
#pragma unroll
    for (int tile = 0; tile < 8; tile++) {
      acc[tile] = __builtin_amdgcn_mfma_f32_16x16x32_bf16(wh[tile], xh[tt].v, acc[tile], 0, 0, 0);
      acc[tile] = __builtin_amdgcn_mfma_f32_16x16x32_bf16(wh[tile], xl[tt].v, acc[tile], 0, 0, 0);
      acc[tile] = __builtin_amdgcn_mfma_f32_16x16x32_bf16(wl[tile], xh[tt].v, acc[tile], 0, 0, 0);
    }
#pragma unroll
    for (int i = 0; i < 4; i++) {
#pragma unroll
      for (int r = 0; r < 4; r++) {
        float h1 = acc[i][r], h2 = acc[i + 4][r];
        float g = h2 / (1.f + __expf(-h1));
        unsigned short gh, gl; hilo(g, gh, gl);
        int j = t * 64 + i * 16 + quad * 4 + r;
        xhi[xbase + (size_t)j * 8] = gh;
        xlo[xbase + (size_t)j * 8] = gl;
      }
    }
  }
}

// ---- K6: kv partials via MFMA. A = packed v2p hi/lo, B = x hi/lo.
// grid (6 jt, NS, 16 b); wave handles all 8 m-tiles x 32 j (2 j-frags).
__global__ __launch_bounds__(256) void k_kv(const unsigned short* __restrict__ xhi,
    const unsigned short* __restrict__ xlo,
    const unsigned short* __restrict__ v2pkhi, const unsigned short* __restrict__ v2pklo,
    float* __restrict__ kvpart) {
  int tid = threadIdx.x, wv = tid >> 6, lane = tid & 63;
  int quad = lane >> 4, l16 = lane & 15;
  int jt = blockIdx.x, nsI = blockIdx.y, b = blockIdx.z;
  int NS = gridDim.y, kPer = NN / NS;
  int j0 = jt * 128 + wv * 32;
  f32x4 zz = {0.f, 0.f, 0.f, 0.f};
  f32x4 acc[8][2];
#pragma unroll
  for (int t = 0; t < 8; t++) { acc[t][0] = zz; acc[t][1] = zz; }
  int kend = nsI * kPer + kPer;
  for (int k0 = nsI * kPer; k0 < kend; k0 += 32) {
    size_t abase = ((size_t)(k0 >> 5) * 4 + quad) * (MM * 8);
    bf16x8 ah[8], al[8];
#pragma unroll
    for (int tile = 0; tile < 8; tile++) {
      size_t off = abase + (size_t)(tile * 16 + l16) * 8;
      ah[tile] = *(const bf16x8*)(v2pkhi + off);
      al[tile] = *(const bf16x8*)(v2pklo + off);
    }
    bf16x8 bh[2], bl[2];
#pragma unroll
    for (int jf = 0; jf < 2; jf++) {
      size_t off = ((size_t)(b * (NN / 8) + (k0 >> 3) + quad) * TC + j0 + jf * 16 + l16) * 8;
      bh[jf] = *(const bf16x8*)(xhi + off);
      bl[jf] = *(const bf16x8*)(xlo + off);
    }
#pragma unroll
    for (int tile = 0; tile < 8; tile++) {
#pragma unroll
      for (int jf = 0; jf < 2; jf++) {
        acc[tile][jf] = __builtin_amdgcn_mfma_f32_16x16x32_bf16(ah[tile], bh[jf], acc[tile][jf], 0, 0, 0);
        acc[tile][jf] = __builtin_amdgcn_mfma_f32_16x16x32_bf16(ah[tile], bl[jf], acc[tile][jf], 0, 0, 0);
        acc[tile][jf] = __builtin_amdgcn_mfma_f32_16x16x32_bf16(al[tile], bh[jf], acc[tile][jf], 0, 0, 0);
      }
    }
  }
  float* dst = kvpart + (size_t)(nsI * BB + b) * KVELEM;
#pragma unroll
  for (int tile = 0; tile < 8; tile++)
#pragma unroll
    for (int jf = 0; jf < 2; jf++)
#pragma unroll
      for (int r = 0; r < 4; r++)
        dst[(size_t)(tile * 16 + quad * 4 + r) * TC + j0 + jf * 16 + l16] = acc[tile][jf][r];
}

// K6b: reduce NS partials, emit kvB hi/lo planes [b][m/8][j][m%8]
__global__ __launch_bounds__(256) void k_kvred(const float* __restrict__ kvpart,
    unsigned short* __restrict__ kvBhi, unsigned short* __restrict__ kvBlo, int NS) {
  int gid = blockIdx.x * 256 + threadIdx.x;   // 196608
  int j = gid % TC; int rest = gid / TC; int mgrp = rest & 15; int b = rest >> 4;
  float s[8];
#pragma unroll
  for (int mi = 0; mi < 8; mi++) s[mi] = 0.f;
  for (int ns = 0; ns < NS; ns++) {
    const float* p = kvpart + ((size_t)(ns * BB + b) * MM + mgrp * 8) * TC + j;
#pragma unroll
    for (int mi = 0; mi < 8; mi++) s[mi] += p[(size_t)mi * TC];
  }
  unsigned short hs[8] __attribute__((aligned(16)));
  unsigned short ls[8] __attribute__((aligned(16)));
#pragma unroll
  for (int mi = 0; mi < 8; mi++) hilo(s[mi], hs[mi], ls[mi]);
  size_t off = ((size_t)(b * 16 + mgrp) * TC + j) * 8;
  *(uint4*)(kvBhi + off) = *(const uint4*)hs;
  *(uint4*)(kvBlo + off) = *(const uint4*)ls;
}

// ---- K7: num = v1p . kv via MFMA, scale by invden, write [B,H,N,T].
// grid (256 nt, 16 b); wave: 16 n x 16 h x all 12 t. Swapped-operand MFMA
// (D transposed: 16 lanes = 16 consecutive n).
// BATCH-LOADED kvB frags: all 24 loads of a ks-iteration hoisted into
// register arrays before the MFMA burst (VGPR_Count was 76 — compiler
// kept MLP ~2; explicit hoist gives 24 outstanding L2 loads per wave).
__global__ __launch_bounds__(256) void k_num(const unsigned short* __restrict__ v1phi,
    const unsigned short* __restrict__ v1plo, const unsigned short* __restrict__ kvBhi,
    const unsigned short* __restrict__ kvBlo, const float* __restrict__ invden,
    float* __restrict__ out) {
  int tid = threadIdx.x, wv = tid >> 6, lane = tid & 63;
  int quad = lane >> 4, l16 = lane & 15;
  int nt = blockIdx.x, b = blockIdx.y;
  int n0 = nt * 16;
  int h0 = wv * 16;
  f32x4 zz = {0.f, 0.f, 0.f, 0.f};
  f32x4 acc[12];
#pragma unroll
  for (int t = 0; t < 12; t++) acc[t] = zz;
#pragma unroll
  for (int ks = 0; ks < 4; ks++) {
    size_t aoff0 = (size_t)(n0 + l16) * MM + ks * 32 + quad * 8;
    bf16x8 a0h = *(const bf16x8*)(v1phi + aoff0);
    bf16x8 a0l = *(const bf16x8*)(v1plo + aoff0);
    bf16x8 bh[12], bl[12];
#pragma unroll
    for (int t = 0; t < 12; t++) {
      int j = t * 64 + h0 + l16;
      size_t boff = ((size_t)(b * 16 + ks * 4 + quad) * TC + j) * 8;
      bh[t] = *(const bf16x8*)(kvBhi + boff);
      bl[t] = *(const bf16x8*)(kvBlo + boff);
    }
#pragma unroll
    for (int t = 0; t < 12; t++) {
      acc[t] = __builtin_amdgcn_mfma_f32_16x16x32_bf16(bh[t], a0h, acc[t], 0, 0, 0);
      acc[t] = __builtin_amdgcn_mfma_f32_16x16x32_bf16(bl[t], a0h, acc[t], 0, 0, 0);
      acc[t] = __builtin_amdgcn_mfma_f32_16x16x32_bf16(bh[t], a0l, acc[t], 0, 0, 0);
    }
  }
  int n = n0 + l16;
  float idn = invden[n];
#pragma unroll
  for (int r = 0; r < 4; r++) {
    int h = h0 + quad * 4 + r;
    float o[12];
#pragma unroll
    for (int t = 0; t < 12; t++) o[t] = acc[t][r] * idn;
    float* dst = out + ((size_t)(b * HH + h) * NN + n) * TT;
    *(float4*)(dst) = make_float4(o[0], o[1], o[2], o[3]);
    *(float4*)(dst + 4) = make_float4(o[4], o[5], o[6], o[7]);
    *(float4*)(dst + 8) = make_float4(o[8], o[9], o[10], o[11]);
  }
}

extern "C" void kernel_launch(void* const* d_in, const int* in_sizes, int n_in,
                              void* d_out, int out_size, void* d_ws, size_t ws_size,
                              hipStream_t stream) {
  const float* input = (const float*)d_in[0];
  const float* nv1   = (const float*)d_in[1];
  const float* nv2   = (const float*)d_in[2];
  const float* Wi    = (const float*)d_in[3];
  const float* bi    = (const float*)d_in[4];
  const float* Wo    = (const float*)d_in[5];
  const float* bo    = (const float*)d_in[6];
  const float* proj  = (const float*)d_in[7];
  float* out = (float*)d_out;
  float* v1p = out + V1OFF;
  float* v2p = out + V2OFF;
  // x hi/lo planes alias the out0 region exactly (50331648 shorts each)
  unsigned short* xhi = (unsigned short*)d_out;
  unsigned short* xlo = xhi + 50331648;

  char* wsb = (char*)d_ws;
  const size_t MB = 1 << 20;
  unsigned short* v2pkhi = (unsigned short*)(wsb + 0 * MB);
  unsigned short* v2pklo = (unsigned short*)(wsb + 1 * MB);
  unsigned short* v1phi  = (unsigned short*)(wsb + 2 * MB);
  unsigned short* v1plo  = (unsigned short*)(wsb + 3 * MB);
  unsigned short* whi    = (unsigned short*)(wsb + 4 * MB);
  unsigned short* wlo    = (unsigned short*)(wsb + 4 * MB + 8192);
  float* colsum  = (float*)(wsb + 4 * MB + 16384);
  float* rowmax2 = (float*)(wsb + 4 * MB + 16384 + 512);
  float* stab2   = (float*)(wsb + 4 * MB + 16384 + 512 + 16384);
  float* invden  = (float*)(wsb + 5 * MB);
  unsigned short* kvBhi = (unsigned short*)(wsb + 6 * MB);
  unsigned short* kvBlo = (unsigned short*)(wsb + 10 * MB);
  float* kvpart = (float*)(wsb + 14 * MB);

  // adaptive k-split for kv partials based on available ws
  size_t partBytes = (size_t)BB * KVELEM * 4;
  size_t avail = (ws_size > 14 * MB) ? ws_size - 14 * MB : 0;
  int NS = (avail >= 16 * partBytes) ? 16 :
           (avail >= 8 * partBytes) ? 8 : (avail >= 4 * partBytes ? 4 : 2);

  hipMemsetAsync(colsum, 0, MM * sizeof(float), stream);
  k_wsplit<<<16, 256, 0, stream>>>(Wi, Wo, whi, wlo);
  k_feat<<<NN, 128, 0, stream>>>(nv1, nv2, proj, v1p, v2p, rowmax2, v1phi, v1plo);
  k_stab<<<1, 256, 0, stream>>>(rowmax2, stab2);
  k_v2p<<<64, 128, 0, stream>>>(v2p, stab2, colsum, v2pkhi, v2pklo);
  k_den<<<16, 256, 0, stream>>>(v1p, colsum, invden);
  k_point<<<dim3(3, 64, 16), 256, 0, stream>>>(input, whi, wlo, bi, bo, xhi, xlo);
  k_kv<<<dim3(6, NS, 16), 256, 0, stream>>>(xhi, xlo, v2pkhi, v2pklo, kvpart);
  k_kvred<<<768, 256, 0, stream>>>(kvpart, kvBhi, kvBlo, NS);
  k_num<<<dim3(256, 16), 256, 0, stream>>>(v1phi, v1plo, kvBhi, kvBlo, invden, out);
}